// Round 2
// baseline (372.507 us; speedup 1.0000x reference)
//
#include <hip/hip_runtime.h>
#include <hip/hip_bf16.h>

typedef __bf16 bf16;
typedef bf16 bf16x8 __attribute__((ext_vector_type(8)));
typedef bf16 bf16x4v __attribute__((ext_vector_type(4)));
typedef bf16 bf16x2v __attribute__((ext_vector_type(2)));
typedef float f32x4 __attribute__((ext_vector_type(4)));

#define D_MODEL 1024
#define SEQ     2048
#define BATCH   4
#define NHEAD   16
#define HDIM    64
#define MTOK    8192  // BATCH*SEQ

// async global->LDS, 16B per lane, dest = wave-uniform base + lane*16
#define GLD16(src, dst)                                                        \
  __builtin_amdgcn_global_load_lds(                                            \
      (const __attribute__((address_space(1))) void*)(src),                    \
      (__attribute__((address_space(3))) void*)(dst), 16, 0, 0)

template <int CTRL>
__device__ __forceinline__ float dppf(float x) {
  return __builtin_bit_cast(
      float, __builtin_amdgcn_mov_dpp(__builtin_bit_cast(int, x), CTRL, 0xF, 0xF, true));
}
// reduce across the 16-lane column group (quad xor1, xor2, half-mirror, mirror)
__device__ __forceinline__ float red16_max(float x) {
  x = fmaxf(x, dppf<0xB1>(x));
  x = fmaxf(x, dppf<0x4E>(x));
  x = fmaxf(x, dppf<0x141>(x));
  x = fmaxf(x, dppf<0x140>(x));
  return x;
}
__device__ __forceinline__ float red16_sum(float x) {
  x += dppf<0xB1>(x);
  x += dppf<0x4E>(x);
  x += dppf<0x141>(x);
  x += dppf<0x140>(x);
  return x;
}

// ---------------- prep: x fp32 -> bf16 ----------------
__global__ __launch_bounds__(256) void cvt_x_kernel(const float* __restrict__ x,
                                                    bf16* __restrict__ xb) {
  int i = blockIdx.x * 256 + threadIdx.x;
  f32x4 v = ((const f32x4*)x)[i];
  bf16x4v o;
#pragma unroll
  for (int c = 0; c < 4; ++c) o[c] = (bf16)v[c];
  ((bf16x4v*)xb)[i] = o;
}

// ---------------- prep: W[k][n] fp32 -> Wt[n][k] bf16 (tiled transpose) ----------------
__global__ __launch_bounds__(256) void wtrans_kernel(
    const float* __restrict__ Wq, const float* __restrict__ Wk,
    const float* __restrict__ Wv, const float* __restrict__ Wo,
    bf16* __restrict__ wt, bf16* __restrict__ wot) {
  __shared__ float t[32][33];
  int z = blockIdx.z;
  const float* W = (z == 0) ? Wq : (z == 1) ? Wk : (z == 2) ? Wv : Wo;
  bf16* dst = (z < 3) ? (wt + (size_t)z * D_MODEL * D_MODEL) : wot;
  int tx = threadIdx.x, ty = threadIdx.y;
  int bx = blockIdx.x * 32, by = blockIdx.y * 32;
#pragma unroll
  for (int j = 0; j < 4; ++j)
    t[ty + j * 8][tx] = W[(size_t)(by + ty + j * 8) * D_MODEL + bx + tx];
  __syncthreads();
#pragma unroll
  for (int j = 0; j < 4; ++j)
    dst[(size_t)(bx + ty + j * 8) * D_MODEL + by + tx] = (bf16)t[tx][ty + j * 8];
}

// ---------------- GEMM: C[M,n] = A[M,1024] * Bt[n,1024]^T (+bias) ----------------
// MODE 0: QKV fused (grid.x=24 -> N=3072). Output scattered to qkv[3][B][H][S][Hd] bf16,
//         Q portion scaled by 1/8 (1/sqrt(Hd)).
// MODE 1: out-projection (grid.x=8 -> N=1024). Output fp32 row-major + bias.
template <int MODE>
__global__ __launch_bounds__(256) void gemm_bt(
    const bf16* __restrict__ A, const bf16* __restrict__ Bt,
    const float* __restrict__ bias0, const float* __restrict__ bias1,
    const float* __restrict__ bias2, void* __restrict__ outp) {
  __shared__ bf16 As[128 * 32];
  __shared__ bf16 Bs[128 * 32];
  const int tid = threadIdx.x;
  const int wave = tid >> 6, lane = tid & 63;
  const int rowBase = blockIdx.y * 128;
  const int colBase = blockIdx.x * 128;
  const int wR = (wave >> 1) * 64;
  const int wC = (wave & 1) * 64;

  // staging map: idx = i*256+tid, LDS byte = idx*16, row = idx>>2 (64B rows), chunk c = idx&3
  // global source chunk = c ^ ((row>>1)&3)  (XOR swizzle so frag ds_read_b128 is ~conflict-free)
  const int r0 = tid >> 2, c0 = tid & 3;
  const int cp0 = c0 ^ ((r0 >> 1) & 3);
  const int r1 = 64 + r0;
  const int cp1 = c0 ^ ((r1 >> 1) & 3);
  const bf16* srcA0 = A + (size_t)(rowBase + r0) * 1024 + cp0 * 8;
  const bf16* srcA1 = A + (size_t)(rowBase + r1) * 1024 + cp1 * 8;
  const bf16* srcB0 = Bt + (size_t)(colBase + r0) * 1024 + cp0 * 8;
  const bf16* srcB1 = Bt + (size_t)(colBase + r1) * 1024 + cp1 * 8;
  char* AsB = (char*)As;
  char* BsB = (char*)Bs;
  char* ldsA0 = AsB + wave * 1024;
  char* ldsA1 = AsB + 4096 + wave * 1024;
  char* ldsB0 = BsB + wave * 1024;
  char* ldsB1 = BsB + 4096 + wave * 1024;

  int aoff[4], boff[4];
#pragma unroll
  for (int i = 0; i < 4; ++i) {
    int ra = wR + i * 16 + (lane & 15);
    aoff[i] = ra * 64 + (((lane >> 4) ^ ((ra >> 1) & 3)) * 16);
    int rb = wC + i * 16 + (lane & 15);
    boff[i] = rb * 64 + (((lane >> 4) ^ ((rb >> 1) & 3)) * 16);
  }

  f32x4 acc[4][4] = {};
  for (int k0 = 0; k0 < 1024; k0 += 32) {
    GLD16(srcA0 + k0, ldsA0);
    GLD16(srcA1 + k0, ldsA1);
    GLD16(srcB0 + k0, ldsB0);
    GLD16(srcB1 + k0, ldsB1);
    __syncthreads();
    bf16x8 af[4], bf_[4];
#pragma unroll
    for (int i = 0; i < 4; ++i) af[i] = *(const bf16x8*)(AsB + aoff[i]);
#pragma unroll
    for (int i = 0; i < 4; ++i) bf_[i] = *(const bf16x8*)(BsB + boff[i]);
#pragma unroll
    for (int mi = 0; mi < 4; ++mi)
#pragma unroll
      for (int ni = 0; ni < 4; ++ni)
        acc[mi][ni] =
            __builtin_amdgcn_mfma_f32_16x16x32_bf16(af[mi], bf_[ni], acc[mi][ni], 0, 0, 0);
    __syncthreads();
  }

  // C/D layout: col = lane&15, row = (lane>>4)*4 + r   [m89/m91 verified]
  const int rl = (lane >> 4) * 4;
  const int cl = lane & 15;
  if (MODE == 0) {
    bf16* qkvb = (bf16*)outp;
#pragma unroll
    for (int mi = 0; mi < 4; ++mi) {
      int rbase = rowBase + wR + mi * 16 + rl;
#pragma unroll
      for (int ni = 0; ni < 4; ++ni) {
        int col = colBase + wC + ni * 16 + cl;
        int mat = col >> 10, nn = col & 1023;
        int hh = nn >> 6, dd = nn & 63;
        const float* bp = (mat == 0) ? bias0 : (mat == 1) ? bias1 : bias2;
        float scl = (mat == 0) ? 0.125f : 1.0f;
        float bvv = bp[nn];
        bf16* dst = qkvb + (size_t)mat * ((size_t)MTOK * D_MODEL);
#pragma unroll
        for (int r = 0; r < 4; ++r) {
          int m = rbase + r;
          int bb = m >> 11, ss = m & 2047;
          dst[((size_t)(bb * NHEAD + hh) * SEQ + ss) * HDIM + dd] =
              (bf16)((acc[mi][ni][r] + bvv) * scl);
        }
      }
    }
  } else {
    float* dst = (float*)outp;
#pragma unroll
    for (int mi = 0; mi < 4; ++mi) {
      int rbase = rowBase + wR + mi * 16 + rl;
#pragma unroll
      for (int ni = 0; ni < 4; ++ni) {
        int col = colBase + wC + ni * 16 + cl;
        float bvv = bias0[col];
#pragma unroll
        for (int r = 0; r < 4; ++r)
          dst[(size_t)(rbase + r) * 1024 + col] = acc[mi][ni][r] + bvv;
      }
    }
  }
}

// ---------------- flash attention ----------------
// grid (16 q-tiles, 16 heads, 4 batch), 256 threads. QBLK=128 (32 rows/wave), KV tile = 64.
// qkv layout [3][B*H][S][Hd] bf16 (Q pre-scaled by 1/8). ctx out: [B][S][H*Hd] bf16.
__global__ __launch_bounds__(256) void attn_kernel(const bf16* __restrict__ qkv,
                                                   bf16* __restrict__ ctx) {
  __shared__ bf16 Ks[64 * 64];      // [key][dim], chunk-swizzled
  __shared__ bf16 Vt[64 * 64];      // [dim][key] (transposed), chunk-swizzled
  __shared__ bf16 Ps[4][32 * 64];   // per-wave P tile [qrow][key], chunk-swizzled
  const int tid = threadIdx.x;
  const int wave = tid >> 6, lane = tid & 63;
  const int qt = blockIdx.x, hh = blockIdx.y, bb = blockIdx.z;
  const int bh = bb * NHEAD + hh;
  const bf16* Qp = qkv + (size_t)bh * SEQ * HDIM;
  const bf16* Kp = Qp + (size_t)MTOK * D_MODEL;
  const bf16* Vp = Kp + (size_t)MTOK * D_MODEL;
  char* KsB = (char*)Ks;
  char* VtB = (char*)Vt;
  char* PsB = (char*)(Ps[wave]);

  const int l15 = lane & 15, l16 = lane >> 4;

  // Q fragments held in registers for whole kernel
  bf16x8 qf[2][2];
  const int qrow0 = qt * 128 + wave * 32;
#pragma unroll
  for (int mi = 0; mi < 2; ++mi)
#pragma unroll
    for (int ks = 0; ks < 2; ++ks)
      qf[mi][ks] =
          *(const bf16x8*)(Qp + (size_t)(qrow0 + mi * 16 + l15) * 64 + ks * 32 + l16 * 8);

  const f32x4 ZERO4 = {0.f, 0.f, 0.f, 0.f};
  const f32x4 NEG4 = {-1e30f, -1e30f, -1e30f, -1e30f};
  f32x4 o[2][4] = {};
  f32x4 m_run[2] = {NEG4, NEG4};
  f32x4 l_run[2] = {ZERO4, ZERO4};

  // K staging: rows of 128B (64 bf16), 8 threads/row, source chunk = c ^ (row&7)
  const int krow0 = tid >> 3, kc = tid & 7;
  const int kcp0 = kc ^ (krow0 & 7);
  const int krow1 = 32 + krow0;
  const int kcp1 = kc ^ (krow1 & 7);
  const bf16* srcK0 = Kp + (size_t)krow0 * 64 + kcp0 * 8;
  const bf16* srcK1 = Kp + (size_t)krow1 * 64 + kcp1 * 8;
  char* ldsK0 = KsB + wave * 1024;
  char* ldsK1 = KsB + 4096 + wave * 1024;
  // V staging: thread handles key pair (2*vp, 2*vp+1), dims vd0..vd0+7
  const int vp = tid >> 3, vd0 = (tid & 7) * 8;

  int koff[4][2], voff[4][2], poff[2][2];
#pragma unroll
  for (int ni = 0; ni < 4; ++ni)
#pragma unroll
    for (int ks = 0; ks < 2; ++ks) {
      int key = ni * 16 + l15;
      koff[ni][ks] = key * 128 + (((ks * 4 + l16) ^ (key & 7)) * 16);
      int d = ni * 16 + l15;
      int f = (d & 7) ^ ((d >> 3) & 7);
      voff[ni][ks] = d * 128 + (((ks * 4 + l16) ^ f) * 16);
    }
#pragma unroll
  for (int mi = 0; mi < 2; ++mi)
#pragma unroll
    for (int ks = 0; ks < 2; ++ks) {
      int row = mi * 16 + l15;
      poff[mi][ks] = row * 128 + (((ks * 4 + l16) ^ (row & 7)) * 16);
    }

  for (int kt = 0; kt < 32; ++kt) {
    const size_t gkoff = (size_t)kt * 64 * 64;
    // stage K (async, linear LDS dest, swizzled global source)
    GLD16(srcK0 + gkoff, ldsK0);
    GLD16(srcK1 + gkoff, ldsK1);
    // stage V transposed into Vt via registers (swizzled chunks)
    bf16x8 v0 = *(const bf16x8*)(Vp + gkoff + (size_t)(2 * vp) * 64 + vd0);
    bf16x8 v1 = *(const bf16x8*)(Vp + gkoff + (size_t)(2 * vp + 1) * 64 + vd0);
#pragma unroll
    for (int j = 0; j < 8; ++j) {
      int d = vd0 + j;
      int f = (d & 7) ^ ((d >> 3) & 7);
      bf16x2v pr;
      pr[0] = v0[j];
      pr[1] = v1[j];
      *(bf16x2v*)(VtB + d * 128 + (((vp >> 2) ^ f) * 16) + (vp & 3) * 4) = pr;
    }
    __syncthreads();

    // S = Q K^T  (Q pre-scaled)
    f32x4 sa[2][4];
#pragma unroll
    for (int mi = 0; mi < 2; ++mi)
#pragma unroll
      for (int ni = 0; ni < 4; ++ni) sa[mi][ni] = ZERO4;
#pragma unroll
    for (int ni = 0; ni < 4; ++ni)
#pragma unroll
      for (int ks = 0; ks < 2; ++ks) {
        bf16x8 kf = *(const bf16x8*)(KsB + koff[ni][ks]);
#pragma unroll
        for (int mi = 0; mi < 2; ++mi)
          sa[mi][ni] =
              __builtin_amdgcn_mfma_f32_16x16x32_bf16(qf[mi][ks], kf, sa[mi][ni], 0, 0, 0);
      }

    // online softmax (per 16-lane column group, DPP reductions)
#pragma unroll
    for (int mi = 0; mi < 2; ++mi) {
      f32x4 mt;
#pragma unroll
      for (int c = 0; c < 4; ++c)
        mt[c] = fmaxf(fmaxf(sa[mi][0][c], sa[mi][1][c]), fmaxf(sa[mi][2][c], sa[mi][3][c]));
#pragma unroll
      for (int c = 0; c < 4; ++c) mt[c] = red16_max(mt[c]);
      f32x4 mnew, alpha;
#pragma unroll
      for (int c = 0; c < 4; ++c) {
        mnew[c] = fmaxf(m_run[mi][c], mt[c]);
        alpha[c] = __expf(m_run[mi][c] - mnew[c]);
      }
      f32x4 pvv[4];
      f32x4 rsum = ZERO4;
#pragma unroll
      for (int ni = 0; ni < 4; ++ni) {
#pragma unroll
        for (int c = 0; c < 4; ++c) pvv[ni][c] = __expf(sa[mi][ni][c] - mnew[c]);
        rsum += pvv[ni];
      }
#pragma unroll
      for (int c = 0; c < 4; ++c) rsum[c] = red16_sum(rsum[c]);
      l_run[mi] = l_run[mi] * alpha + rsum;
      m_run[mi] = mnew;
#pragma unroll
      for (int nd = 0; nd < 4; ++nd) o[mi][nd] *= alpha;
      // write P tile (wave-private region, swizzled)
#pragma unroll
      for (int ni = 0; ni < 4; ++ni) {
        int key = ni * 16 + l15;
        int cnat = key >> 3;
        int kb2 = (key & 7) * 2;
#pragma unroll
        for (int c = 0; c < 4; ++c) {
          int prow = mi * 16 + l16 * 4 + c;
          *(bf16*)(PsB + prow * 128 + ((cnat ^ (prow & 7)) * 16) + kb2) = (bf16)pvv[ni][c];
        }
      }
    }

    // O += P V  (A = P from LDS, B^T = Vt from LDS)
    bf16x8 pa[2][2];
#pragma unroll
    for (int mi = 0; mi < 2; ++mi)
#pragma unroll
      for (int ks = 0; ks < 2; ++ks) pa[mi][ks] = *(const bf16x8*)(PsB + poff[mi][ks]);
#pragma unroll
    for (int nd = 0; nd < 4; ++nd)
#pragma unroll
      for (int ks = 0; ks < 2; ++ks) {
        bf16x8 vf = *(const bf16x8*)(VtB + voff[nd][ks]);
#pragma unroll
        for (int mi = 0; mi < 2; ++mi)
          o[mi][nd] = __builtin_amdgcn_mfma_f32_16x16x32_bf16(pa[mi][ks], vf, o[mi][nd], 0, 0, 0);
      }
    __syncthreads();
  }

  // epilogue: divide by row sums, write ctx [B][S][H*Hd]
#pragma unroll
  for (int mi = 0; mi < 2; ++mi)
#pragma unroll
    for (int nd = 0; nd < 4; ++nd) {
      int d = nd * 16 + l15;
#pragma unroll
      for (int r = 0; r < 4; ++r) {
        int srow = qrow0 + mi * 16 + l16 * 4 + r;
        float val = o[mi][nd][r] / l_run[mi][r];
        ctx[(size_t)(bb * SEQ + srow) * D_MODEL + hh * HDIM + d] = (bf16)val;
      }
    }
}

extern "C" void kernel_launch(void* const* d_in, const int* in_sizes, int n_in,
                              void* d_out, int out_size, void* d_ws, size_t ws_size,
                              hipStream_t stream) {
  const float* x  = (const float*)d_in[0];
  const float* Wq = (const float*)d_in[1];
  const float* bq = (const float*)d_in[2];
  const float* Wk = (const float*)d_in[3];
  const float* bk = (const float*)d_in[4];
  const float* Wv = (const float*)d_in[5];
  const float* bv = (const float*)d_in[6];
  const float* Wo = (const float*)d_in[7];
  const float* bo = (const float*)d_in[8];

  char* ws = (char*)d_ws;
  bf16* xb   = (bf16*)(ws);                              // 16 MB  x in bf16
  bf16* wt   = (bf16*)(ws + (size_t)16 * 1024 * 1024);   //  6 MB  Wq^T,Wk^T,Wv^T bf16
  bf16* wot  = (bf16*)(ws + (size_t)22 * 1024 * 1024);   //  2 MB  Wo^T bf16
  bf16* qkvb = (bf16*)(ws + (size_t)24 * 1024 * 1024);   // 48 MB  Q,K,V [3][B*H][S][Hd]
  bf16* ctxb = (bf16*)(ws + (size_t)72 * 1024 * 1024);   // 16 MB  ctx [B][S][D]

  cvt_x_kernel<<<8192, 256, 0, stream>>>(x, xb);
  wtrans_kernel<<<dim3(32, 32, 4), dim3(32, 8), 0, stream>>>(Wq, Wk, Wv, Wo, wt, wot);
  gemm_bt<0><<<dim3(24, 64), 256, 0, stream>>>(xb, wt, bq, bk, bv, (void*)qkvb);
  attn_kernel<<<dim3(16, 16, 4), 256, 0, stream>>>(qkvb, ctxb);
  gemm_bt<1><<<dim3(8, 64), 256, 0, stream>>>(ctxb, wot, bo, bo, bo, d_out);
}

// Round 3
// 295.790 us; speedup vs baseline: 1.2594x; 1.2594x over previous
//
#include <hip/hip_runtime.h>
#include <hip/hip_bf16.h>

typedef __bf16 bf16;
typedef bf16 bf16x8 __attribute__((ext_vector_type(8)));
typedef bf16 bf16x4v __attribute__((ext_vector_type(4)));
typedef bf16 bf16x2v __attribute__((ext_vector_type(2)));
typedef float f32x4 __attribute__((ext_vector_type(4)));
typedef float f32x16 __attribute__((ext_vector_type(16)));
typedef unsigned int uint;
typedef uint uint4v __attribute__((ext_vector_type(4)));

#define D_MODEL 1024
#define SEQ     2048
#define BATCH   4
#define NHEAD   16
#define HDIM    64
#define MTOK    8192  // BATCH*SEQ
#define RSZ     ((size_t)MTOK * D_MODEL)   // one Q/K/V region, elements
// 1/sqrt(64) * log2(e): softmax done in exp2 domain
#define QSCALE  0.18033688011112042f

// async global->LDS, 16B per lane, dest = wave-uniform base (+lane*16 by HW)
#define GLD16(src, dst)                                                        \
  __builtin_amdgcn_global_load_lds(                                            \
      (const __attribute__((address_space(1))) void*)(src),                    \
      (__attribute__((address_space(3))) void*)(dst), 16, 0, 0)

// v_permlane32_swap_b32: swaps a's upper 32 lanes with b's lower 32 lanes
#define PSWAP(a, b) asm("v_permlane32_swap_b32 %0, %1" : "+v"(a), "+v"(b))

__device__ __forceinline__ uint pk2(float lo, float hi) {
  bf16x2v h;
  h[0] = (bf16)lo;
  h[1] = (bf16)hi;
  return __builtin_bit_cast(uint, h);
}

// ---------------- prep: x fp32 -> bf16 ----------------
__global__ __launch_bounds__(256) void cvt_x_kernel(const float* __restrict__ x,
                                                    bf16* __restrict__ xb) {
  int i = blockIdx.x * 256 + threadIdx.x;
  f32x4 v = ((const f32x4*)x)[i];
  bf16x4v o;
#pragma unroll
  for (int c = 0; c < 4; ++c) o[c] = (bf16)v[c];
  ((bf16x4v*)xb)[i] = o;
}

// ---------------- prep: W[k][n] fp32 -> Wt[n][k] bf16 (tiled transpose) ----------------
__global__ __launch_bounds__(256) void wtrans_kernel(
    const float* __restrict__ Wq, const float* __restrict__ Wk,
    const float* __restrict__ Wv, const float* __restrict__ Wo,
    bf16* __restrict__ wt, bf16* __restrict__ wot) {
  __shared__ float t[32][33];
  int z = blockIdx.z;
  const float* W = (z == 0) ? Wq : (z == 1) ? Wk : (z == 2) ? Wv : Wo;
  bf16* dst = (z < 3) ? (wt + (size_t)z * D_MODEL * D_MODEL) : wot;
  int tx = threadIdx.x, ty = threadIdx.y;
  int bx = blockIdx.x * 32, by = blockIdx.y * 32;
#pragma unroll
  for (int j = 0; j < 4; ++j)
    t[ty + j * 8][tx] = W[(size_t)(by + ty + j * 8) * D_MODEL + bx + tx];
  __syncthreads();
#pragma unroll
  for (int j = 0; j < 4; ++j)
    dst[(size_t)(bx + ty + j * 8) * D_MODEL + by + tx] = (bf16)t[tx][ty + j * 8];
}

// ---------------- GEMM: C[M,n] = A[M,1024] * Bt[n,1024]^T (+bias) ----------------
// MODE 0: QKV fused (grid.x=24 -> N=3072). Q,K -> [bh][s][d] bf16 (Q scaled by
//         QSCALE); V -> TRANSPOSED [bh][d][s] bf16.
// MODE 1: out-projection (grid.x=8 -> N=1024). Output fp32 row-major + bias.
template <int MODE>
__global__ __launch_bounds__(256) void gemm_bt(
    const bf16* __restrict__ A, const bf16* __restrict__ Bt,
    const float* __restrict__ bias0, const float* __restrict__ bias1,
    const float* __restrict__ bias2, void* __restrict__ outp) {
  __shared__ bf16 As[128 * 32];
  __shared__ bf16 Bs[128 * 32];
  const int tid = threadIdx.x;
  const int wave = tid >> 6, lane = tid & 63;
  const int rowBase = blockIdx.y * 128;
  const int colBase = blockIdx.x * 128;
  const int wR = (wave >> 1) * 64;
  const int wC = (wave & 1) * 64;

  const int r0 = tid >> 2, c0 = tid & 3;
  const int cp0 = c0 ^ ((r0 >> 1) & 3);
  const int r1 = 64 + r0;
  const int cp1 = c0 ^ ((r1 >> 1) & 3);
  const bf16* srcA0 = A + (size_t)(rowBase + r0) * 1024 + cp0 * 8;
  const bf16* srcA1 = A + (size_t)(rowBase + r1) * 1024 + cp1 * 8;
  const bf16* srcB0 = Bt + (size_t)(colBase + r0) * 1024 + cp0 * 8;
  const bf16* srcB1 = Bt + (size_t)(colBase + r1) * 1024 + cp1 * 8;
  char* AsB = (char*)As;
  char* BsB = (char*)Bs;
  char* ldsA0 = AsB + wave * 1024;
  char* ldsA1 = AsB + 4096 + wave * 1024;
  char* ldsB0 = BsB + wave * 1024;
  char* ldsB1 = BsB + 4096 + wave * 1024;

  int aoff[4], boff[4];
#pragma unroll
  for (int i = 0; i < 4; ++i) {
    int ra = wR + i * 16 + (lane & 15);
    aoff[i] = ra * 64 + (((lane >> 4) ^ ((ra >> 1) & 3)) * 16);
    int rb = wC + i * 16 + (lane & 15);
    boff[i] = rb * 64 + (((lane >> 4) ^ ((rb >> 1) & 3)) * 16);
  }

  f32x4 acc[4][4] = {};
  for (int k0 = 0; k0 < 1024; k0 += 32) {
    GLD16(srcA0 + k0, ldsA0);
    GLD16(srcA1 + k0, ldsA1);
    GLD16(srcB0 + k0, ldsB0);
    GLD16(srcB1 + k0, ldsB1);
    __syncthreads();
    bf16x8 af[4], bf_[4];
#pragma unroll
    for (int i = 0; i < 4; ++i) af[i] = *(const bf16x8*)(AsB + aoff[i]);
#pragma unroll
    for (int i = 0; i < 4; ++i) bf_[i] = *(const bf16x8*)(BsB + boff[i]);
#pragma unroll
    for (int mi = 0; mi < 4; ++mi)
#pragma unroll
      for (int ni = 0; ni < 4; ++ni)
        acc[mi][ni] =
            __builtin_amdgcn_mfma_f32_16x16x32_bf16(af[mi], bf_[ni], acc[mi][ni], 0, 0, 0);
    __syncthreads();
  }

  // C/D layout: col = lane&15, row = (lane>>4)*4 + r
  const int rl = (lane >> 4) * 4;
  const int cl = lane & 15;
  if (MODE == 0) {
    bf16* qkvb = (bf16*)outp;
#pragma unroll
    for (int mi = 0; mi < 4; ++mi) {
      int rbase = rowBase + wR + mi * 16 + rl;
#pragma unroll
      for (int ni = 0; ni < 4; ++ni) {
        int col = colBase + wC + ni * 16 + cl;
        int mat = col >> 10, nn = col & 1023;
        int hh = nn >> 6, dd = nn & 63;
        if (mat == 2) {
          // V: write transposed Vt[bh][dd][ss], 4 consecutive ss -> 8B store
          float bvv = bias2[nn];
          bf16x4v p4;
#pragma unroll
          for (int r = 0; r < 4; ++r) p4[r] = (bf16)(acc[mi][ni][r] + bvv);
          int bb = rbase >> 11, ss = rbase & 2047;
          *(bf16x4v*)(qkvb + 2 * RSZ +
                      ((size_t)(bb * NHEAD + hh) * HDIM + dd) * SEQ + ss) = p4;
        } else {
          const float* bp = (mat == 0) ? bias0 : bias1;
          float scl = (mat == 0) ? QSCALE : 1.0f;
          float bvv = bp[nn];
          bf16* dst = qkvb + (size_t)mat * RSZ;
#pragma unroll
          for (int r = 0; r < 4; ++r) {
            int m = rbase + r;
            int bb = m >> 11, ss = m & 2047;
            dst[((size_t)(bb * NHEAD + hh) * SEQ + ss) * HDIM + dd] =
                (bf16)((acc[mi][ni][r] + bvv) * scl);
          }
        }
      }
    }
  } else {
    float* dst = (float*)outp;
#pragma unroll
    for (int mi = 0; mi < 4; ++mi) {
      int rbase = rowBase + wR + mi * 16 + rl;
#pragma unroll
      for (int ni = 0; ni < 4; ++ni) {
        int col = colBase + wC + ni * 16 + cl;
        float bvv = bias0[col];
#pragma unroll
        for (int r = 0; r < 4; ++r)
          dst[(size_t)(rbase + r) * 1024 + col] = acc[mi][ni][r] + bvv;
      }
    }
  }
}

// ---------------- flash attention, 32x32 MFMA, swapped operands ----------------
// grid (16 q-tiles, 16 heads, 4 batch), 256 threads = 4 waves, 32 q-rows/wave.
// Q,K: [bh][s][64] bf16 (Q pre-scaled by QSCALE); Vt: [bh][64 d][s] bf16.
// Per KV tile (64 keys): S^T = mfma(K,Q) -> lane-local q-row softmax (exp2
// domain) -> P packed in-register (cvt_pk + permlane32_swap) -> O^T = mfma(Vt,P).
__global__ __launch_bounds__(256, 3) void attn_kernel(const bf16* __restrict__ qkv,
                                                      bf16* __restrict__ ctx) {
  __shared__ __align__(16) char smem[32768];
  char* Kbuf = smem;          // [2][8192]
  char* Vbuf = smem + 16384;  // [2][8192]

  const int tid = threadIdx.x;
  const int wave = tid >> 6, lane = tid & 63;
  const int l31 = lane & 31, l5 = lane >> 5;
  const int qt = blockIdx.x, hh = blockIdx.y, bb = blockIdx.z;
  const int bh = bb * NHEAD + hh;
  const bf16* Qp = qkv + (size_t)bh * SEQ * HDIM;
  const bf16* Kp = qkv + RSZ + (size_t)bh * SEQ * HDIM;
  const bf16* Vtp = qkv + 2 * RSZ + (size_t)bh * HDIM * SEQ;

  // Q fragments (B operand): lane holds Q[qrow][16*kc + 8*l5 + j]
  const int qrow = qt * 128 + wave * 32 + l31;
  bf16x8 qf[4];
#pragma unroll
  for (int kc = 0; kc < 4; ++kc)
    qf[kc] = *(const bf16x8*)(Qp + (size_t)qrow * 64 + kc * 16 + l5 * 8);

  // staging addresses: thread handles rows r0 and r0+32, slot (tid&7),
  // global source slot XOR-swizzled by (row&7) so LDS stays linear.
  const int sr = tid >> 3;
  const int sz = (tid & 7) ^ (sr & 7);
  const bf16* srcK0 = Kp + sr * 64 + sz * 8;
  const bf16* srcK1 = Kp + (sr + 32) * 64 + sz * 8;
  const bf16* srcV0 = Vtp + (size_t)sr * SEQ + sz * 8;
  const bf16* srcV1 = Vtp + (size_t)(sr + 32) * SEQ + sz * 8;

#define STAGE(sel, t)                                                     \
  do {                                                                    \
    GLD16(srcK0 + (t) * 4096, Kbuf + (sel) * 8192 + wave * 1024);         \
    GLD16(srcK1 + (t) * 4096, Kbuf + (sel) * 8192 + 4096 + wave * 1024);  \
    GLD16(srcV0 + (t) * 64, Vbuf + (sel) * 8192 + wave * 1024);           \
    GLD16(srcV1 + (t) * 64, Vbuf + (sel) * 8192 + 4096 + wave * 1024);    \
  } while (0)

  f32x16 o[2];
#pragma unroll
  for (int nd = 0; nd < 2; ++nd)
#pragma unroll
    for (int r = 0; r < 16; ++r) o[nd][r] = 0.f;
  float m_run = -1e30f, l_run = 0.f;

  STAGE(0, 0);
  __syncthreads();

  for (int kt = 0; kt < 32; ++kt) {
    const int cur = kt & 1;
    if (kt < 31) STAGE(cur ^ 1, kt + 1);

    const char* Kc = Kbuf + cur * 8192;
    const char* Vc = Vbuf + cur * 8192;

    // S^T = K . Q^T  (A = K rows, B = Q rows)
    f32x16 s[2];
#pragma unroll
    for (int nb = 0; nb < 2; ++nb)
#pragma unroll
      for (int r = 0; r < 16; ++r) s[nb][r] = 0.f;
#pragma unroll
    for (int nb = 0; nb < 2; ++nb)
#pragma unroll
      for (int kc = 0; kc < 4; ++kc) {
        int row = nb * 32 + l31;
        int off = row * 128 + (((2 * kc + l5) ^ (row & 7)) * 16);
        bf16x8 kf = *(const bf16x8*)(Kc + off);
        s[nb] = __builtin_amdgcn_mfma_f32_32x32x16_bf16(kf, qf[kc], s[nb], 0, 0, 0);
      }

    // ---- softmax (lane-local q-row; keys split with lane^32) ----
    float t8[8];
#pragma unroll
    for (int r = 0; r < 8; ++r)
      t8[r] = fmaxf(fmaxf(s[0][r], s[0][r + 8]), fmaxf(s[1][r], s[1][r + 8]));
#pragma unroll
    for (int r = 0; r < 4; ++r) t8[r] = fmaxf(t8[r], t8[r + 4]);
    float pmax = fmaxf(fmaxf(t8[0], t8[1]), fmaxf(t8[2], t8[3]));
    pmax = fmaxf(pmax, __shfl_xor(pmax, 32, 64));

    // defer-max: skip O rescale unless the running max grew by > 8 (log2)
    if (!__all(pmax - m_run <= 8.0f)) {
      float mnew = fmaxf(m_run, pmax);
      float al = __builtin_amdgcn_exp2f(m_run - mnew);
      m_run = mnew;
      l_run *= al;
#pragma unroll
      for (int nd = 0; nd < 2; ++nd)
#pragma unroll
        for (int r = 0; r < 16; ++r) o[nd][r] *= al;
    }
#pragma unroll
    for (int nb = 0; nb < 2; ++nb)
#pragma unroll
      for (int r = 0; r < 16; ++r)
        s[nb][r] = __builtin_amdgcn_exp2f(s[nb][r] - m_run);

    f32x16 tv = s[0] + s[1];
    float q8[8];
#pragma unroll
    for (int r = 0; r < 8; ++r) q8[r] = tv[r] + tv[r + 8];
#pragma unroll
    for (int r = 0; r < 4; ++r) q8[r] += q8[r + 4];
    float rs = (q8[0] + q8[1]) + (q8[2] + q8[3]);
    rs += __shfl_xor(rs, 32, 64);
    l_run += rs;

    // ---- pack P into PV B-fragments (in-register, no LDS) ----
    bf16x8 pf[4];
#pragma unroll
    for (int cc = 0; cc < 4; ++cc) {
      const int nb = cc >> 1, b0 = (cc & 1) * 8;
      uint w0 = pk2(s[nb][b0 + 0], s[nb][b0 + 1]);
      uint w1 = pk2(s[nb][b0 + 2], s[nb][b0 + 3]);
      uint w2 = pk2(s[nb][b0 + 4], s[nb][b0 + 5]);
      uint w3 = pk2(s[nb][b0 + 6], s[nb][b0 + 7]);
      PSWAP(w0, w2);
      PSWAP(w1, w3);
      uint4v u = {w0, w1, w2, w3};
      pf[cc] = __builtin_bit_cast(bf16x8, u);
    }

    // O^T += Vt . P^T  (A = Vt rows, B = P rows)
#pragma unroll
    for (int nd = 0; nd < 2; ++nd)
#pragma unroll
      for (int cc = 0; cc < 4; ++cc) {
        int row = nd * 32 + l31;
        int off = row * 128 + (((2 * cc + l5) ^ (row & 7)) * 16);
        bf16x8 vf = *(const bf16x8*)(Vc + off);
        o[nd] = __builtin_amdgcn_mfma_f32_32x32x16_bf16(vf, pf[cc], o[nd], 0, 0, 0);
      }
    __syncthreads();
  }

  // epilogue: O^T lane holds q = qrow, d = 32*nd + 8*a + 4*l5 + b
  const float inv = 1.0f / l_run;
  bf16* crow = ctx + (size_t)(bb * SEQ + qrow) * D_MODEL + hh * HDIM;
#pragma unroll
  for (int nd = 0; nd < 2; ++nd)
#pragma unroll
    for (int a = 0; a < 4; ++a) {
      bf16x4v p4;
#pragma unroll
      for (int b = 0; b < 4; ++b) p4[b] = (bf16)(o[nd][4 * a + b] * inv);
      *(bf16x4v*)(crow + nd * 32 + a * 8 + l5 * 4) = p4;
    }
#undef STAGE
}

extern "C" void kernel_launch(void* const* d_in, const int* in_sizes, int n_in,
                              void* d_out, int out_size, void* d_ws, size_t ws_size,
                              hipStream_t stream) {
  const float* x  = (const float*)d_in[0];
  const float* Wq = (const float*)d_in[1];
  const float* bq = (const float*)d_in[2];
  const float* Wk = (const float*)d_in[3];
  const float* bk = (const float*)d_in[4];
  const float* Wv = (const float*)d_in[5];
  const float* bv = (const float*)d_in[6];
  const float* Wo = (const float*)d_in[7];
  const float* bo = (const float*)d_in[8];

  char* ws = (char*)d_ws;
  bf16* xb   = (bf16*)(ws);                              // 16 MB  x in bf16
  bf16* wt   = (bf16*)(ws + (size_t)16 * 1024 * 1024);   //  6 MB  Wq^T,Wk^T,Wv^T bf16
  bf16* wot  = (bf16*)(ws + (size_t)22 * 1024 * 1024);   //  2 MB  Wo^T bf16
  bf16* qkvb = (bf16*)(ws + (size_t)24 * 1024 * 1024);   // 48 MB  Q,K [bh][s][d]; Vt [bh][d][s]
  bf16* ctxb = (bf16*)(ws + (size_t)72 * 1024 * 1024);   // 16 MB  ctx [B][S][D]

  cvt_x_kernel<<<8192, 256, 0, stream>>>(x, xb);
  wtrans_kernel<<<dim3(32, 32, 4), dim3(32, 8), 0, stream>>>(Wq, Wk, Wv, Wo, wt, wot);
  gemm_bt<0><<<dim3(24, 64), 256, 0, stream>>>(xb, wt, bq, bk, bv, (void*)qkvb);
  attn_kernel<<<dim3(16, 16, 4), 256, 0, stream>>>(qkvb, ctxb);
  gemm_bt<1><<<dim3(8, 64), 256, 0, stream>>>(ctxb, wot, bo, bo, bo, d_out);
}